// Round 9
// baseline (256.955 us; speedup 1.0000x reference)
//
#include <hip/hip_runtime.h>

typedef short v8s __attribute__((ext_vector_type(8)));
typedef float v4f __attribute__((ext_vector_type(4)));

#define LOG2E 1.44269504088896340736f

// ---- d_ws layout (bytes) ----
#define WS_FBF_T 0u          // u16 [8][4096][64]  f transposed (n-major, MFMA rows)
#define WS_FVP   4194304u    // u16 [8][64][4096]  f c-major, per-32 key-permuted cols
#define WS_G     8388608u    // f32 [8][4096]      row squared-norms
#define WS_BMAX  8519680u    // f32 [8][64]        per-chunk partial max of g
#define WS_NEED  8521728u

__device__ __forceinline__ unsigned short f2bf_rne(float f) {
  unsigned int u = __builtin_bit_cast(unsigned int, f);
  u += 0x7FFFu + ((u >> 16) & 1u);
  return (unsigned short)(u >> 16);
}

__device__ __forceinline__ unsigned int pack_hi16(float hi, float lo) {
#if defined(__has_builtin) && __has_builtin(__builtin_amdgcn_perm)
  return __builtin_amdgcn_perm(__builtin_bit_cast(unsigned int, hi),
                               __builtin_bit_cast(unsigned int, lo), 0x07060302u);
#else
  return (__builtin_bit_cast(unsigned int, hi) & 0xFFFF0000u) |
         (__builtin_bit_cast(unsigned int, lo) >> 16);
#endif
}

// ============ pre-pass (R4 LDS-pivot form, proven) — UNCHANGED ============
__global__ __launch_bounds__(512) void prep_kernel(
    const float* __restrict__ x, unsigned short* __restrict__ fbf_t,
    unsigned short* __restrict__ fvp, float* __restrict__ g, float* __restrict__ bmax) {
  __shared__ __align__(16) unsigned short T[64 * 66];  // [c][nn], pitch 66
  __shared__ float red[8][64];
  const int t = threadIdx.x;
  const int b = blockIdx.x >> 6, ch = blockIdx.x & 63;
  const int n0 = ch << 6, nn = t & 63, cg = t >> 6;

  float sq = 0.f;
#pragma unroll
  for (int j = 0; j < 8; ++j) {
    const int c = cg * 8 + j;
    float v = x[((size_t)(b * 64 + c) << 12) + n0 + nn];
    sq = __builtin_fmaf(v, v, sq);
    T[c * 66 + nn] = f2bf_rne(v);
  }
  red[cg][nn] = sq;
  __syncthreads();

  if (t < 64) {
    float tot = ((red[0][t] + red[1][t]) + (red[2][t] + red[3][t])) +
                ((red[4][t] + red[5][t]) + (red[6][t] + red[7][t]));
    g[b * 4096 + n0 + t] = tot;
    float m = tot;
    m = fmaxf(m, __shfl_xor(m, 1, 64));
    m = fmaxf(m, __shfl_xor(m, 2, 64));
    m = fmaxf(m, __shfl_xor(m, 4, 64));
    m = fmaxf(m, __shfl_xor(m, 8, 64));
    m = fmaxf(m, __shfl_xor(m, 16, 64));
    m = fmaxf(m, __shfl_xor(m, 32, 64));
    if (t == 0) bmax[b * 64 + ch] = m;
  }

  {
    const int nt = t >> 3, q8 = t & 7;
    unsigned short u[8];
#pragma unroll
    for (int j = 0; j < 8; ++j) u[j] = T[(q8 * 8 + j) * 66 + nt];
    *(v8s*)&fbf_t[((size_t)b << 18) + (size_t)(n0 + nt) * 64 + q8 * 8] = *(v8s*)u;
  }

  {
    const int c = t >> 3, s8 = t & 7;
    const int base = c * 66 + ((s8 >> 2) << 5) + ((s8 & 3) << 2);
    unsigned int w0 = *(const unsigned int*)&T[base];
    unsigned int w1 = *(const unsigned int*)&T[base + 2];
    unsigned int w2 = *(const unsigned int*)&T[base + 16];
    unsigned int w3 = *(const unsigned int*)&T[base + 18];
    uint4 uu;
    uu.x = w0; uu.y = w1; uu.z = w2; uu.w = w3;
    *(uint4*)&fvp[((size_t)(b * 64 + c) << 12) + n0 + s8 * 8] = uu;
  }
}

// one QK->exp->pack->PV unit: identical numerics to the proven R0/R3 jq-block
#define QKPV(JQ, AK, AV)                                                        \
  {                                                                             \
    v4f s0 = (v4f){0.f, 0.f, 0.f, 0.f}, s1 = (v4f){0.f, 0.f, 0.f, 0.f};         \
    _Pragma("unroll")                                                           \
    for (int cs = 0; cs < 2; ++cs) {                                            \
      s0 = __builtin_amdgcn_mfma_f32_16x16x32_bf16(AK[0][cs], bQ[JQ][cs], s0,   \
                                                   0, 0, 0);                    \
      s1 = __builtin_amdgcn_mfma_f32_16x16x32_bf16(AK[1][cs], bQ[JQ][cs], s1,   \
                                                   0, 0, 0);                    \
    }                                                                           \
    float p0[4], p1[4];                                                         \
    _Pragma("unroll")                                                           \
    for (int r = 0; r < 4; ++r) {                                               \
      p0[r] = __builtin_amdgcn_exp2f(__builtin_fmaf(s0[r], LOG2E, -msc[JQ]));   \
      p1[r] = __builtin_amdgcn_exp2f(__builtin_fmaf(s1[r], LOG2E, -msc[JQ]));   \
    }                                                                           \
    rsum[JQ] += ((p0[0] + p0[1]) + (p0[2] + p0[3])) +                           \
                ((p1[0] + p1[1]) + (p1[2] + p1[3]));                            \
    uint4 up;                                                                   \
    up.x = pack_hi16(p0[1], p0[0]);                                             \
    up.y = pack_hi16(p0[3], p0[2]);                                             \
    up.z = pack_hi16(p1[1], p1[0]);                                             \
    up.w = pack_hi16(p1[3], p1[2]);                                             \
    v8s bp = __builtin_bit_cast(v8s, up);                                       \
    _Pragma("unroll")                                                           \
    for (int ct = 0; ct < 4; ++ct)                                              \
      oacc[ct][JQ] = __builtin_amdgcn_mfma_f32_16x16x32_bf16(AV[ct], bp,        \
                                                             oacc[ct][JQ],      \
                                                             0, 0, 0);          \
  }

// ============ main: R7 body (correctness-proven), launch bound (1024, 1) ============
// Empirical decode of hipcc's 2nd launch_bounds arg = min BLOCKS per CU:
//   (512,2)->cap 128 [R0/R3/R4/R8: 104-128, no spill]; (512,4)/(1024,4)/bare
//   (1024)->cap 64 [R1/R2/R6/R7; R6/R7 spilled the jq=4 body].
// (1024, 1): one 1024-thr block/CU = 16 waves/CU = 4 waves/SIMD, VGPR cap 128
// >= the body's measured 112-register need. This is the final untested cell:
// {4 waves/SIMD, ratio-4, 16 barriers, staging once per CU, double-buffered}.
// Tripwires: VGPR must be ~112-128 and WRITE_SIZE ~8 MB (no spill).
__global__ __launch_bounds__(1024, 1) void chanattn_main(
    const float* __restrict__ x, const unsigned short* __restrict__ fbf_t,
    const unsigned short* __restrict__ fvp, const float* __restrict__ g,
    const float* __restrict__ bmax, float* __restrict__ out) {
  __shared__ __align__(16) unsigned char smem[145408];
  unsigned short* sKt = (unsigned short*)smem;             // [256][72] u16 per buf
  unsigned short* sVc = (unsigned short*)(smem + 36864);   // [64][264] u16 per buf
  float* lred = (float*)(smem + 141312);                   // [128][8] f32
  const int PAIR = 35328;  // u16 offset between buffer pairs (36864B + 33792B)

  const int tid = threadIdx.x;
  const int wave = tid >> 6, lane = tid & 63, quad = lane >> 4, l15 = lane & 15;
  const int qg = wave >> 3, kg = wave & 7;   // 2 qg x 8 kg
  const int b = blockIdx.x >> 5, qt = blockIdx.x & 31;

  const unsigned short* fT = fbf_t + ((size_t)b << 18);  // [n][c]
  const unsigned short* fV = fvp + ((size_t)b << 18);    // [c][n'] permuted

  const int sKey = tid >> 3, sC = (tid & 7) << 3;   // K: rows sKey, sKey+128
  const int vC = tid >> 4, vK = (tid & 15) << 3;    // V: c=vC, slots vK, vK+128

  float gm = bmax[b * 64 + lane];
  gm = fmaxf(gm, __shfl_xor(gm, 1, 64));
  gm = fmaxf(gm, __shfl_xor(gm, 2, 64));
  gm = fmaxf(gm, __shfl_xor(gm, 4, 64));
  gm = fmaxf(gm, __shfl_xor(gm, 8, 64));
  gm = fmaxf(gm, __shfl_xor(gm, 16, 64));
  gm = fmaxf(gm, __shfl_xor(gm, 32, 64));
  float gq[4];
#pragma unroll
  for (int jq = 0; jq < 4; ++jq)
    gq[jq] = g[b * 4096 + qt * 128 + qg * 64 + jq * 16 + l15];

  // Q fragments direct from global (one-time read; validated R5-R8 numerics)
  v8s bQ[4][2];
#pragma unroll
  for (int jq = 0; jq < 4; ++jq)
#pragma unroll
    for (int cs = 0; cs < 2; ++cs)
      bQ[jq][cs] = *(const v8s*)&fT[(size_t)(qt * 128 + qg * 64 + jq * 16 + l15) * 64 +
                                    cs * 32 + quad * 8];
  float msc[4];
#pragma unroll
  for (int jq = 0; jq < 4; ++jq) msc[jq] = __builtin_sqrtf(gq[jq] * gm) * LOG2E;

  // ---- prologue: tile 0 -> buf0, issue tile-1 loads ----
  v8s pfk[2], pfv[2];
#pragma unroll
  for (int i = 0; i < 2; ++i)
    pfk[i] = *(const v8s*)&fT[(size_t)(sKey + i * 128) * 64 + sC];
#pragma unroll
  for (int j = 0; j < 2; ++j)
    pfv[j] = *(const v8s*)&fV[(size_t)vC * 4096 + vK + j * 128];
#pragma unroll
  for (int i = 0; i < 2; ++i)
    *(v8s*)&sKt[(sKey + i * 128) * 72 + sC] = pfk[i];
#pragma unroll
  for (int j = 0; j < 2; ++j)
    *(v8s*)&sVc[vC * 264 + vK + j * 128] = pfv[j];
#pragma unroll
  for (int i = 0; i < 2; ++i)
    pfk[i] = *(const v8s*)&fT[(size_t)(256 + sKey + i * 128) * 64 + sC];
#pragma unroll
  for (int j = 0; j < 2; ++j)
    pfv[j] = *(const v8s*)&fV[(size_t)vC * 4096 + 256 + vK + j * 128];

  v4f oacc[4][4];
  float rsum[4];
#pragma unroll
  for (int ct = 0; ct < 4; ++ct)
#pragma unroll
    for (int jq = 0; jq < 4; ++jq) oacc[ct][jq] = (v4f){0.f, 0.f, 0.f, 0.f};
#pragma unroll
  for (int jq = 0; jq < 4; ++jq) rsum[jq] = 0.f;

  for (int kt = 0; kt < 16; ++kt) {
    __syncthreads();
    const int po = (kt & 1) * PAIR;
    const int pn = po ^ PAIR;

    // this wave's 32-key fragments for tile kt
    v8s aK[2][2];
#pragma unroll
    for (int t = 0; t < 2; ++t)
#pragma unroll
      for (int cs = 0; cs < 2; ++cs)
        aK[t][cs] =
            *(const v8s*)&sKt[po + (kg * 32 + t * 16 + l15) * 72 + cs * 32 + quad * 8];
    v8s aV[4];
#pragma unroll
    for (int ct = 0; ct < 4; ++ct)
      aV[ct] = *(const v8s*)&sVc[po + (ct * 16 + l15) * 264 + kg * 32 + quad * 8];

    QKPV(0, aK, aV);   // MFMA in flight before staging writes (R3 pattern)

    if (kt < 15) {
#pragma unroll
      for (int i = 0; i < 2; ++i)
        *(v8s*)&sKt[pn + (sKey + i * 128) * 72 + sC] = pfk[i];
#pragma unroll
      for (int j = 0; j < 2; ++j)
        *(v8s*)&sVc[pn + vC * 264 + vK + j * 128] = pfv[j];
    }
    if (kt < 14) {
      const int k0 = (kt + 2) << 8;
#pragma unroll
      for (int i = 0; i < 2; ++i)
        pfk[i] = *(const v8s*)&fT[(size_t)(k0 + sKey + i * 128) * 64 + sC];
#pragma unroll
      for (int j = 0; j < 2; ++j)
        pfv[j] = *(const v8s*)&fV[(size_t)vC * 4096 + k0 + vK + j * 128];
    }

#pragma unroll
    for (int jq = 1; jq < 4; ++jq) QKPV(jq, aK, aV);
  }

  // ---- epilogue ----
#pragma unroll
  for (int jq = 0; jq < 4; ++jq) {
    float s = rsum[jq];
    s += __shfl_xor(s, 16, 64);
    s += __shfl_xor(s, 32, 64);
    rsum[jq] = s;
  }
  if (quad == 0) {
#pragma unroll
    for (int jq = 0; jq < 4; ++jq)
      lred[(qg * 64 + jq * 16 + l15) * 8 + kg] = rsum[jq];
  }
  __syncthreads();
  float inv[4];
#pragma unroll
  for (int jq = 0; jq < 4; ++jq) {
    const float4 lv0 = *(const float4*)&lred[(qg * 64 + jq * 16 + l15) * 8];
    const float4 lv1 = *(const float4*)&lred[(qg * 64 + jq * 16 + l15) * 8 + 4];
    inv[jq] = __builtin_amdgcn_rcpf(((lv0.x + lv0.y) + (lv0.z + lv0.w)) +
                                    ((lv1.x + lv1.y) + (lv1.z + lv1.w)));
  }
  __syncthreads();   // lred read done; Obuf (smem base) may now be written

  float* Obuf = (float*)smem;   // [2 qg][64 c][68 q] = 34816 B (lred untouched)
#pragma unroll
  for (int round = 0; round < 8; ++round) {
    if (kg == round) {
#pragma unroll
      for (int ct = 0; ct < 4; ++ct)
#pragma unroll
        for (int jq = 0; jq < 4; ++jq)
#pragma unroll
          for (int r = 0; r < 4; ++r) {
            float val = oacc[ct][jq][r] * inv[jq];
            float* p = &Obuf[(qg * 64 + ct * 16 + quad * 4 + r) * 68 + jq * 16 + l15];
            if (round == 0) *p = val; else *p += val;
          }
    }
    __syncthreads();
  }
#pragma unroll
  for (int j = 0; j < 2; ++j) {
    int idx = tid + j * 1024;
    int qg2 = idx >> 10, c = (idx >> 4) & 63, q4 = idx & 15;
    const float4 o = *(const float4*)&Obuf[(qg2 * 64 + c) * 68 + q4 * 4];
    size_t gidx = ((size_t)(b * 64 + c) << 12) + (unsigned)(qt * 128 + qg2 * 64 + q4 * 4);
    const float4 xv = *(const float4*)(x + gidx);
    float4 rv;
    rv.x = xv.x + o.x; rv.y = xv.y + o.y; rv.z = xv.z + o.z; rv.w = xv.w + o.w;
    *(float4*)(out + gidx) = rv;
  }
}

// ============ fallback (R1 kernel, proven correct) if ws too small ============
__global__ __launch_bounds__(512) void
chanattn_fallback(const float* __restrict__ x, float* __restrict__ out) {
  __shared__ __align__(16) unsigned char smem[54272];
  unsigned short* sKt = (unsigned short*)smem;
  unsigned short* sVc = (unsigned short*)(smem + 18432);
  unsigned short* sP  = (unsigned short*)(smem + 35840);
  const int tid = threadIdx.x;
  const int wave = tid >> 6, lane = tid & 63, quad = lane >> 4, l15 = lane & 15;
  const int b = blockIdx.x & 7, qt = blockIdx.x >> 3;
  const float* fb = x + (size_t)b * (64 * 4096);
  const int skey = tid & 127, sc0 = (tid >> 7) << 4;
  {
    float vq[16];
#pragma unroll
    for (int j = 0; j < 16; ++j) vq[j] = fb[(sc0 + j) * 4096 + qt * 128 + skey];
    unsigned short us[16];
#pragma unroll
    for (int j = 0; j < 16; ++j) us[j] = f2bf_rne(vq[j]);
#pragma unroll
    for (int h = 0; h < 2; ++h) {
      v8s t;
#pragma unroll
      for (int j = 0; j < 8; ++j) t[j] = (short)us[h * 8 + j];
      *(v8s*)&sKt[skey * 72 + sc0 + h * 8] = t;
    }
  }
  float vk[16];
#pragma unroll
  for (int j = 0; j < 16; ++j) vk[j] = fb[(sc0 + j) * 4096 + skey];
  __syncthreads();
  v8s aq[2];
#pragma unroll
  for (int cs = 0; cs < 2; ++cs)
    aq[cs] = *(const v8s*)&sKt[(wave * 16 + l15) * 72 + cs * 32 + quad * 8];
  __syncthreads();
  v4f oacc[4];
#pragma unroll
  for (int ct = 0; ct < 4; ++ct) oacc[ct] = (v4f){0.f, 0.f, 0.f, 0.f};
  float m_run[4], l_run[4];
#pragma unroll
  for (int r = 0; r < 4; ++r) { m_run[r] = -3.0e38f; l_run[r] = 0.f; }
  unsigned short* sPw = sP + wave * (16 * 72);
  for (int kt = 0; kt < 32; ++kt) {
    {
      unsigned short us[16];
#pragma unroll
      for (int j = 0; j < 16; ++j) us[j] = f2bf_rne(vk[j]);
#pragma unroll
      for (int h = 0; h < 2; ++h) {
        v8s t;
#pragma unroll
        for (int j = 0; j < 8; ++j) t[j] = (short)us[h * 8 + j];
        *(v8s*)&sKt[skey * 72 + sc0 + h * 8] = t;
      }
#pragma unroll
      for (int j = 0; j < 16; ++j) sVc[(sc0 + j) * 136 + skey] = us[j];
    }
    __syncthreads();
    if (kt + 1 < 32) {
      const int m0 = (kt + 1) * 128;
#pragma unroll
      for (int j = 0; j < 16; ++j) vk[j] = fb[(sc0 + j) * 4096 + m0 + skey];
    }
    v4f sacc[8];
#pragma unroll
    for (int t = 0; t < 8; ++t) {
      v4f acc = (v4f){0.f, 0.f, 0.f, 0.f};
#pragma unroll
      for (int cs = 0; cs < 2; ++cs) {
        v8s bf = *(const v8s*)&sKt[(t * 16 + l15) * 72 + cs * 32 + quad * 8];
        acc = __builtin_amdgcn_mfma_f32_16x16x32_bf16(aq[cs], bf, acc, 0, 0, 0);
      }
      sacc[t] = acc;
    }
    float alpha[4], msc[4], rsum[4];
#pragma unroll
    for (int r = 0; r < 4; ++r) {
      float mv = sacc[0][r];
#pragma unroll
      for (int t = 1; t < 8; ++t) mv = fmaxf(mv, sacc[t][r]);
      mv = fmaxf(mv, __shfl_xor(mv, 8, 64));
      mv = fmaxf(mv, __shfl_xor(mv, 4, 64));
      mv = fmaxf(mv, __shfl_xor(mv, 2, 64));
      mv = fmaxf(mv, __shfl_xor(mv, 1, 64));
      float mnew = fmaxf(m_run[r], mv);
      alpha[r] = __builtin_amdgcn_exp2f((m_run[r] - mnew) * LOG2E);
      m_run[r] = mnew;
      msc[r] = mnew * LOG2E;
      l_run[r] *= alpha[r];
      rsum[r] = 0.f;
    }
#pragma unroll
    for (int ct = 0; ct < 4; ++ct)
#pragma unroll
      for (int r = 0; r < 4; ++r) oacc[ct][r] *= alpha[r];
#pragma unroll
    for (int half = 0; half < 2; ++half) {
#pragma unroll
      for (int t = half * 4; t < half * 4 + 4; ++t)
#pragma unroll
        for (int r = 0; r < 4; ++r) {
          float p = __builtin_amdgcn_exp2f(__builtin_fmaf(sacc[t][r], LOG2E, -msc[r]));
          rsum[r] += p;
          sPw[(quad * 4 + r) * 72 + (t - half * 4) * 16 + l15] = f2bf_rne(p);
        }
      asm volatile("s_waitcnt lgkmcnt(0)" ::: "memory");
#pragma unroll
      for (int ms = 0; ms < 2; ++ms) {
        v8s af = *(const v8s*)&sPw[l15 * 72 + ms * 32 + quad * 8];
#pragma unroll
        for (int ct = 0; ct < 4; ++ct) {
          v8s bf = *(const v8s*)&sVc[(ct * 16 + l15) * 136 + (half * 2 + ms) * 32 + quad * 8];
          oacc[ct] = __builtin_amdgcn_mfma_f32_16x16x32_bf16(af, bf, oacc[ct], 0, 0, 0);
        }
      }
      asm volatile("s_waitcnt lgkmcnt(0)" ::: "memory");
    }
#pragma unroll
    for (int r = 0; r < 4; ++r) {
      float s = rsum[r];
      s += __shfl_xor(s, 8, 64);
      s += __shfl_xor(s, 4, 64);
      s += __shfl_xor(s, 2, 64);
      s += __shfl_xor(s, 1, 64);
      l_run[r] += s;
    }
    __syncthreads();
  }
  float inv[4];
#pragma unroll
  for (int r = 0; r < 4; ++r) inv[r] = __builtin_amdgcn_rcpf(l_run[r]);
  float* sOt = (float*)smem;
#pragma unroll
  for (int ct = 0; ct < 4; ++ct)
#pragma unroll
    for (int r = 0; r < 4; ++r)
      sOt[(ct * 16 + l15) * 132 + wave * 16 + quad * 4 + r] = oacc[ct][r] * inv[r];
  __syncthreads();
#pragma unroll
  for (int j = 0; j < 4; ++j) {
    int idx = tid + j * 512;
    int nv = idx & 31, c = idx >> 5;
    float4 o = *(const float4*)&sOt[c * 132 + nv * 4];
    size_t gaddr = (size_t)b * (64 * 4096) + (size_t)c * 4096 + (size_t)(qt * 128 + nv * 4);
    float4 xv = *(const float4*)(x + gaddr);
    float4 res = make_float4(xv.x + o.x, xv.y + o.y, xv.z + o.z, xv.w + o.w);
    *(float4*)(out + gaddr) = res;
  }
}

extern "C" void kernel_launch(void* const* d_in, const int* in_sizes, int n_in,
                              void* d_out, int out_size, void* d_ws, size_t ws_size,
                              hipStream_t stream) {
  const float* xin = (const float*)d_in[0];
  float* out = (float*)d_out;
  if (ws_size >= (size_t)WS_NEED) {
    unsigned short* fbf_t = (unsigned short*)((char*)d_ws + WS_FBF_T);
    unsigned short* fvp = (unsigned short*)((char*)d_ws + WS_FVP);
    float* g = (float*)((char*)d_ws + WS_G);
    float* bmax = (float*)((char*)d_ws + WS_BMAX);
    prep_kernel<<<dim3(512), dim3(512), 0, stream>>>(xin, fbf_t, fvp, g, bmax);
    chanattn_main<<<dim3(256), dim3(1024), 0, stream>>>(xin, fbf_t, fvp, g, bmax, out);
  } else {
    chanattn_fallback<<<dim3(256), dim3(512), 0, stream>>>(xin, out);
  }
}

// Round 10
// 100.880 us; speedup vs baseline: 2.5471x; 2.5471x over previous
//
#include <hip/hip_runtime.h>

typedef short v8s __attribute__((ext_vector_type(8)));
typedef float v4f __attribute__((ext_vector_type(4)));

#define LOG2E 1.44269504088896340736f

// ---- d_ws layout (bytes) ----
#define WS_FBF_T 0u          // u16 [8][4096][64]  f transposed (n-major, MFMA rows)
#define WS_FVP   4194304u    // u16 [8][64][4096]  f c-major, per-32 key-permuted cols
#define WS_G     8388608u    // f32 [8][4096]      row squared-norms
#define WS_BMAX  8519680u    // f32 [8][64]        per-chunk partial max of g
#define WS_NEED  8521728u

__device__ __forceinline__ unsigned short f2bf_rne(float f) {
  unsigned int u = __builtin_bit_cast(unsigned int, f);
  u += 0x7FFFu + ((u >> 16) & 1u);
  return (unsigned short)(u >> 16);
}

__device__ __forceinline__ unsigned int pack_hi16(float hi, float lo) {
#if defined(__has_builtin) && __has_builtin(__builtin_amdgcn_perm)
  return __builtin_amdgcn_perm(__builtin_bit_cast(unsigned int, hi),
                               __builtin_bit_cast(unsigned int, lo), 0x07060302u);
#else
  return (__builtin_bit_cast(unsigned int, hi) & 0xFFFF0000u) |
         (__builtin_bit_cast(unsigned int, lo) >> 16);
#endif
}

// ============ pre-pass (R4 LDS-pivot form, proven) ============
__global__ __launch_bounds__(512) void prep_kernel(
    const float* __restrict__ x, unsigned short* __restrict__ fbf_t,
    unsigned short* __restrict__ fvp, float* __restrict__ g, float* __restrict__ bmax) {
  __shared__ __align__(16) unsigned short T[64 * 66];  // [c][nn], pitch 66
  __shared__ float red[8][64];
  const int t = threadIdx.x;
  const int b = blockIdx.x >> 6, ch = blockIdx.x & 63;
  const int n0 = ch << 6, nn = t & 63, cg = t >> 6;

  float sq = 0.f;
#pragma unroll
  for (int j = 0; j < 8; ++j) {
    const int c = cg * 8 + j;
    float v = x[((size_t)(b * 64 + c) << 12) + n0 + nn];
    sq = __builtin_fmaf(v, v, sq);
    T[c * 66 + nn] = f2bf_rne(v);
  }
  red[cg][nn] = sq;
  __syncthreads();

  if (t < 64) {
    float tot = ((red[0][t] + red[1][t]) + (red[2][t] + red[3][t])) +
                ((red[4][t] + red[5][t]) + (red[6][t] + red[7][t]));
    g[b * 4096 + n0 + t] = tot;
    float m = tot;
    m = fmaxf(m, __shfl_xor(m, 1, 64));
    m = fmaxf(m, __shfl_xor(m, 2, 64));
    m = fmaxf(m, __shfl_xor(m, 4, 64));
    m = fmaxf(m, __shfl_xor(m, 8, 64));
    m = fmaxf(m, __shfl_xor(m, 16, 64));
    m = fmaxf(m, __shfl_xor(m, 32, 64));
    if (t == 0) bmax[b * 64 + ch] = m;
  }

  {
    const int nt = t >> 3, q8 = t & 7;
    unsigned short u[8];
#pragma unroll
    for (int j = 0; j < 8; ++j) u[j] = T[(q8 * 8 + j) * 66 + nt];
    *(v8s*)&fbf_t[((size_t)b << 18) + (size_t)(n0 + nt) * 64 + q8 * 8] = *(v8s*)u;
  }

  {
    const int c = t >> 3, s8 = t & 7;
    const int base = c * 66 + ((s8 >> 2) << 5) + ((s8 & 3) << 2);
    unsigned int w0 = *(const unsigned int*)&T[base];
    unsigned int w1 = *(const unsigned int*)&T[base + 2];
    unsigned int w2 = *(const unsigned int*)&T[base + 16];
    unsigned int w3 = *(const unsigned int*)&T[base + 18];
    uint4 uu;
    uu.x = w0; uu.y = w1; uu.z = w2; uu.w = w3;
    *(uint4*)&fvp[((size_t)(b * 64 + c) << 12) + n0 + s8 * 8] = uu;
  }
}

// one QK->exp->pack->PV unit: identical numerics to the proven R0 jq-block
#define QKPV(JQ, AK, AV)                                                        \
  {                                                                             \
    v4f s0 = (v4f){0.f, 0.f, 0.f, 0.f}, s1 = (v4f){0.f, 0.f, 0.f, 0.f};         \
    _Pragma("unroll")                                                           \
    for (int cs = 0; cs < 2; ++cs) {                                            \
      s0 = __builtin_amdgcn_mfma_f32_16x16x32_bf16(AK[0][cs], bQ[JQ][cs], s0,   \
                                                   0, 0, 0);                    \
      s1 = __builtin_amdgcn_mfma_f32_16x16x32_bf16(AK[1][cs], bQ[JQ][cs], s1,   \
                                                   0, 0, 0);                    \
    }                                                                           \
    float p0[4], p1[4];                                                         \
    _Pragma("unroll")                                                           \
    for (int r = 0; r < 4; ++r) {                                               \
      p0[r] = __builtin_amdgcn_exp2f(__builtin_fmaf(s0[r], LOG2E, -msc[JQ]));   \
      p1[r] = __builtin_amdgcn_exp2f(__builtin_fmaf(s1[r], LOG2E, -msc[JQ]));   \
    }                                                                           \
    rsum[JQ] += ((p0[0] + p0[1]) + (p0[2] + p0[3])) +                           \
                ((p1[0] + p1[1]) + (p1[2] + p1[3]));                            \
    uint4 up;                                                                   \
    up.x = pack_hi16(p0[1], p0[0]);                                             \
    up.y = pack_hi16(p0[3], p0[2]);                                             \
    up.z = pack_hi16(p1[1], p1[0]);                                             \
    up.w = pack_hi16(p1[3], p1[2]);                                             \
    v8s bp = __builtin_bit_cast(v8s, up);                                       \
    _Pragma("unroll")                                                           \
    for (int ct = 0; ct < 4; ++ct)                                              \
      oacc[ct][JQ] = __builtin_amdgcn_mfma_f32_16x16x32_bf16(AV[ct], bp,        \
                                                             oacc[ct][JQ],      \
                                                             0, 0, 0);          \
  }

// ============ main: CHAMPION RESTORED (R3/R4 form, 47.5 us measured) ============
// Session verdict: {512 thr, (512,2), jq=4, 256-key dbuf tile, 16 barriers,
// staging once} is the only spill-free local optimum. All occupancy avenues
// (2 blk/CU: R1/R8; 1024-thr: R2/R7/R9; (512,4)/(1024,*): 64-VGPR spill wall)
// and the no-staging path (R5: +26 us) were tested and refuted. The remaining
// gap to the 16.6 us MFMA floor is the serial QK->exp->PV chain at the
// 2 waves/SIMD the register file permits — structural, not addressable here.
__global__ __launch_bounds__(512, 2) void chanattn_main(
    const float* __restrict__ x, const unsigned short* __restrict__ fbf_t,
    const unsigned short* __restrict__ fvp, const float* __restrict__ g,
    const float* __restrict__ bmax, float* __restrict__ out) {
  __shared__ __align__(16) unsigned char smem[143360];
  unsigned short* sKtB = (unsigned short*)smem;             // [256][72] u16 per buf
  unsigned short* sVcB = (unsigned short*)(smem + 36864);   // [64][264] u16 per buf
  float* lred = (float*)(smem + 141312);
  const int PAIR = 35328;  // u16 offset between buffer pairs (36864B + 33792B)

  const int tid = threadIdx.x;
  const int wave = tid >> 6, lane = tid & 63, quad = lane >> 4, l15 = lane & 15;
  const int qg = wave >> 2, kg = wave & 3;
  const int b = blockIdx.x >> 5, qt = blockIdx.x & 31;

  const unsigned short* fT = fbf_t + ((size_t)b << 18);  // [n][c]
  const unsigned short* fV = fvp + ((size_t)b << 18);    // [c][n'] permuted

  const int sKey = tid >> 3, sC = (tid & 7) << 3;   // 64 rows x 8 c-chunks per pass
  const int vC = tid >> 4, vK = (tid & 15) << 3;    // 32 ch x 16 key-chunks per pass

  float gm = bmax[b * 64 + lane];
  gm = fmaxf(gm, __shfl_xor(gm, 1, 64));
  gm = fmaxf(gm, __shfl_xor(gm, 2, 64));
  gm = fmaxf(gm, __shfl_xor(gm, 4, 64));
  gm = fmaxf(gm, __shfl_xor(gm, 8, 64));
  gm = fmaxf(gm, __shfl_xor(gm, 16, 64));
  gm = fmaxf(gm, __shfl_xor(gm, 32, 64));
  float gq[4];
#pragma unroll
  for (int jq = 0; jq < 4; ++jq)
    gq[jq] = g[b * 4096 + qt * 128 + qg * 64 + jq * 16 + l15];

  // stage Q tile (128 rows) into buf0 sKt
#pragma unroll
  for (int i = 0; i < 2; ++i)
    *(v8s*)&sKtB[(sKey + i * 64) * 72 + sC] =
        *(const v8s*)&fT[(size_t)(qt * 128 + sKey + i * 64) * 64 + sC];
  // issue tile-0 loads (256 keys)
  v8s pfk[4], pfv[4];
#pragma unroll
  for (int i = 0; i < 4; ++i)
    pfk[i] = *(const v8s*)&fT[(size_t)(sKey + i * 64) * 64 + sC];
#pragma unroll
  for (int i2 = 0; i2 < 2; ++i2)
#pragma unroll
    for (int j = 0; j < 2; ++j)
      pfv[i2 * 2 + j] = *(const v8s*)&fV[(size_t)(vC + i2 * 32) * 4096 + vK + j * 128];

  __syncthreads();
  v8s bQ[4][2];
#pragma unroll
  for (int jq = 0; jq < 4; ++jq)
#pragma unroll
    for (int cs = 0; cs < 2; ++cs)
      bQ[jq][cs] = *(const v8s*)&sKtB[(qg * 64 + jq * 16 + l15) * 72 + cs * 32 + quad * 8];
  float msc[4];
#pragma unroll
  for (int jq = 0; jq < 4; ++jq) msc[jq] = __builtin_sqrtf(gq[jq] * gm) * LOG2E;
  __syncthreads();

  // write tile 0 -> buf0 (fvp pre-permuted: verbatim v8s); issue tile-1 loads
#pragma unroll
  for (int i = 0; i < 4; ++i)
    *(v8s*)&sKtB[(sKey + i * 64) * 72 + sC] = pfk[i];
#pragma unroll
  for (int i2 = 0; i2 < 2; ++i2)
#pragma unroll
    for (int j = 0; j < 2; ++j)
      *(v8s*)&sVcB[(vC + i2 * 32) * 264 + vK + j * 128] = pfv[i2 * 2 + j];
#pragma unroll
  for (int i = 0; i < 4; ++i)
    pfk[i] = *(const v8s*)&fT[(size_t)(256 + sKey + i * 64) * 64 + sC];
#pragma unroll
  for (int i2 = 0; i2 < 2; ++i2)
#pragma unroll
    for (int j = 0; j < 2; ++j)
      pfv[i2 * 2 + j] =
          *(const v8s*)&fV[(size_t)(vC + i2 * 32) * 4096 + 256 + vK + j * 128];

  v4f oacc[4][4];
  float rsum[4];
#pragma unroll
  for (int ct = 0; ct < 4; ++ct)
#pragma unroll
    for (int jq = 0; jq < 4; ++jq) oacc[ct][jq] = (v4f){0.f, 0.f, 0.f, 0.f};
#pragma unroll
  for (int jq = 0; jq < 4; ++jq) rsum[jq] = 0.f;

  for (int kt = 0; kt < 16; ++kt) {
    __syncthreads();
    const int po = (kt & 1) * PAIR;
    const int pn = po ^ PAIR;

    // ---- ks = 0: keys kg*64 .. kg*64+31 ----
    v8s aK[2][2];
#pragma unroll
    for (int t = 0; t < 2; ++t)
#pragma unroll
      for (int cs = 0; cs < 2; ++cs)
        aK[t][cs] =
            *(const v8s*)&sKtB[po + (kg * 64 + t * 16 + l15) * 72 + cs * 32 + quad * 8];
    v8s aV[4];
#pragma unroll
    for (int ct = 0; ct < 4; ++ct)
      aV[ct] = *(const v8s*)&sVcB[po + (ct * 16 + l15) * 264 + kg * 64 + quad * 8];

    QKPV(0, aK, aV);

    if (kt < 15) {
#pragma unroll
      for (int i = 0; i < 4; ++i)
        *(v8s*)&sKtB[pn + (sKey + i * 64) * 72 + sC] = pfk[i];
#pragma unroll
      for (int i2 = 0; i2 < 2; ++i2)
#pragma unroll
        for (int j = 0; j < 2; ++j)
          *(v8s*)&sVcB[pn + (vC + i2 * 32) * 264 + vK + j * 128] = pfv[i2 * 2 + j];
    }
    if (kt < 14) {
      const int k0 = (kt + 2) << 8;
#pragma unroll
      for (int i = 0; i < 4; ++i)
        pfk[i] = *(const v8s*)&fT[(size_t)(k0 + sKey + i * 64) * 64 + sC];
#pragma unroll
      for (int i2 = 0; i2 < 2; ++i2)
#pragma unroll
        for (int j = 0; j < 2; ++j)
          pfv[i2 * 2 + j] =
              *(const v8s*)&fV[(size_t)(vC + i2 * 32) * 4096 + k0 + vK + j * 128];
    }

#pragma unroll
    for (int jq = 1; jq < 4; ++jq) QKPV(jq, aK, aV);

    // ---- ks = 1: keys kg*64+32 .. kg*64+63 ----
    v8s aK1[2][2];
#pragma unroll
    for (int t = 0; t < 2; ++t)
#pragma unroll
      for (int cs = 0; cs < 2; ++cs)
        aK1[t][cs] = *(const v8s*)&sKtB[po + (kg * 64 + 32 + t * 16 + l15) * 72 +
                                        cs * 32 + quad * 8];
    v8s aV1[4];
#pragma unroll
    for (int ct = 0; ct < 4; ++ct)
      aV1[ct] =
          *(const v8s*)&sVcB[po + (ct * 16 + l15) * 264 + kg * 64 + 32 + quad * 8];

#pragma unroll
    for (int jq = 0; jq < 4; ++jq) QKPV(jq, aK1, aV1);
  }

  // ---- epilogue (R0 form) ----
#pragma unroll
  for (int jq = 0; jq < 4; ++jq) {
    float s = rsum[jq];
    s += __shfl_xor(s, 16, 64);
    s += __shfl_xor(s, 32, 64);
    rsum[jq] = s;
  }
  if (quad == 0) {
#pragma unroll
    for (int jq = 0; jq < 4; ++jq)
      lred[(qg * 64 + jq * 16 + l15) * 4 + kg] = rsum[jq];
  }
  __syncthreads();
  float inv[4];
#pragma unroll
  for (int jq = 0; jq < 4; ++jq) {
    const float4 lv = *(const float4*)&lred[(qg * 64 + jq * 16 + l15) * 4];
    inv[jq] = __builtin_amdgcn_rcpf((lv.x + lv.y) + (lv.z + lv.w));
  }

  float* Obuf = (float*)smem;   // [2 qg][64 c][68 q]
#pragma unroll
  for (int round = 0; round < 4; ++round) {
    if (kg == round) {
#pragma unroll
      for (int ct = 0; ct < 4; ++ct)
#pragma unroll
        for (int jq = 0; jq < 4; ++jq)
#pragma unroll
          for (int r = 0; r < 4; ++r) {
            float val = oacc[ct][jq][r] * inv[jq];
            float* p = &Obuf[(qg * 64 + ct * 16 + quad * 4 + r) * 68 + jq * 16 + l15];
            if (round == 0) *p = val; else *p += val;
          }
    }
    __syncthreads();
  }
#pragma unroll
  for (int j = 0; j < 4; ++j) {
    int idx = tid + j * 512;
    int qg2 = idx >> 10, c = (idx >> 4) & 63, q4 = idx & 15;
    const float4 o = *(const float4*)&Obuf[(qg2 * 64 + c) * 68 + q4 * 4];
    size_t gidx = ((size_t)(b * 64 + c) << 12) + (unsigned)(qt * 128 + qg2 * 64 + q4 * 4);
    const float4 xv = *(const float4*)(x + gidx);
    float4 rv;
    rv.x = xv.x + o.x; rv.y = xv.y + o.y; rv.z = xv.z + o.z; rv.w = xv.w + o.w;
    *(float4*)(out + gidx) = rv;
  }
}

// ============ fallback (R1 kernel, proven correct) if ws too small ============
__global__ __launch_bounds__(512) void
chanattn_fallback(const float* __restrict__ x, float* __restrict__ out) {
  __shared__ __align__(16) unsigned char smem[54272];
  unsigned short* sKt = (unsigned short*)smem;
  unsigned short* sVc = (unsigned short*)(smem + 18432);
  unsigned short* sP  = (unsigned short*)(smem + 35840);
  const int tid = threadIdx.x;
  const int wave = tid >> 6, lane = tid & 63, quad = lane >> 4, l15 = lane & 15;
  const int b = blockIdx.x & 7, qt = blockIdx.x >> 3;
  const float* fb = x + (size_t)b * (64 * 4096);
  const int skey = tid & 127, sc0 = (tid >> 7) << 4;
  {
    float vq[16];
#pragma unroll
    for (int j = 0; j < 16; ++j) vq[j] = fb[(sc0 + j) * 4096 + qt * 128 + skey];
    unsigned short us[16];
#pragma unroll
    for (int j = 0; j < 16; ++j) us[j] = f2bf_rne(vq[j]);
#pragma unroll
    for (int h = 0; h < 2; ++h) {
      v8s t;
#pragma unroll
      for (int j = 0; j < 8; ++j) t[j] = (short)us[h * 8 + j];
      *(v8s*)&sKt[skey * 72 + sc0 + h * 8] = t;
    }
  }
  float vk[16];
#pragma unroll
  for (int j = 0; j < 16; ++j) vk[j] = fb[(sc0 + j) * 4096 + skey];
  __syncthreads();
  v8s aq[2];
#pragma unroll
  for (int cs = 0; cs < 2; ++cs)
    aq[cs] = *(const v8s*)&sKt[(wave * 16 + l15) * 72 + cs * 32 + quad * 8];
  __syncthreads();
  v4f oacc[4];
#pragma unroll
  for (int ct = 0; ct < 4; ++ct) oacc[ct] = (v4f){0.f, 0.f, 0.f, 0.f};
  float m_run[4], l_run[4];
#pragma unroll
  for (int r = 0; r < 4; ++r) { m_run[r] = -3.0e38f; l_run[r] = 0.f; }
  unsigned short* sPw = sP + wave * (16 * 72);
  for (int kt = 0; kt < 32; ++kt) {
    {
      unsigned short us[16];
#pragma unroll
      for (int j = 0; j < 16; ++j) us[j] = f2bf_rne(vk[j]);
#pragma unroll
      for (int h = 0; h < 2; ++h) {
        v8s t;
#pragma unroll
        for (int j = 0; j < 8; ++j) t[j] = (short)us[h * 8 + j];
        *(v8s*)&sKt[skey * 72 + sc0 + h * 8] = t;
      }
#pragma unroll
      for (int j = 0; j < 16; ++j) sVc[(sc0 + j) * 136 + skey] = us[j];
    }
    __syncthreads();
    if (kt + 1 < 32) {
      const int m0 = (kt + 1) * 128;
#pragma unroll
      for (int j = 0; j < 16; ++j) vk[j] = fb[(sc0 + j) * 4096 + m0 + skey];
    }
    v4f sacc[8];
#pragma unroll
    for (int t = 0; t < 8; ++t) {
      v4f acc = (v4f){0.f, 0.f, 0.f, 0.f};
#pragma unroll
      for (int cs = 0; cs < 2; ++cs) {
        v8s bf = *(const v8s*)&sKt[(t * 16 + l15) * 72 + cs * 32 + quad * 8];
        acc = __builtin_amdgcn_mfma_f32_16x16x32_bf16(aq[cs], bf, acc, 0, 0, 0);
      }
      sacc[t] = acc;
    }
    float alpha[4], msc[4], rsum[4];
#pragma unroll
    for (int r = 0; r < 4; ++r) {
      float mv = sacc[0][r];
#pragma unroll
      for (int t = 1; t < 8; ++t) mv = fmaxf(mv, sacc[t][r]);
      mv = fmaxf(mv, __shfl_xor(mv, 8, 64));
      mv = fmaxf(mv, __shfl_xor(mv, 4, 64));
      mv = fmaxf(mv, __shfl_xor(mv, 2, 64));
      mv = fmaxf(mv, __shfl_xor(mv, 1, 64));
      float mnew = fmaxf(m_run[r], mv);
      alpha[r] = __builtin_amdgcn_exp2f((m_run[r] - mnew) * LOG2E);
      m_run[r] = mnew;
      msc[r] = mnew * LOG2E;
      l_run[r] *= alpha[r];
      rsum[r] = 0.f;
    }
#pragma unroll
    for (int ct = 0; ct < 4; ++ct)
#pragma unroll
      for (int r = 0; r < 4; ++r) oacc[ct][r] *= alpha[r];
#pragma unroll
    for (int half = 0; half < 2; ++half) {
#pragma unroll
      for (int t = half * 4; t < half * 4 + 4; ++t)
#pragma unroll
        for (int r = 0; r < 4; ++r) {
          float p = __builtin_amdgcn_exp2f(__builtin_fmaf(sacc[t][r], LOG2E, -msc[r]));
          rsum[r] += p;
          sPw[(quad * 4 + r) * 72 + (t - half * 4) * 16 + l15] = f2bf_rne(p);
        }
      asm volatile("s_waitcnt lgkmcnt(0)" ::: "memory");
#pragma unroll
      for (int ms = 0; ms < 2; ++ms) {
        v8s af = *(const v8s*)&sPw[l15 * 72 + ms * 32 + quad * 8];
#pragma unroll
        for (int ct = 0; ct < 4; ++ct) {
          v8s bf = *(const v8s*)&sVc[(ct * 16 + l15) * 136 + (half * 2 + ms) * 32 + quad * 8];
          oacc[ct] = __builtin_amdgcn_mfma_f32_16x16x32_bf16(af, bf, oacc[ct], 0, 0, 0);
        }
      }
      asm volatile("s_waitcnt lgkmcnt(0)" ::: "memory");
    }
#pragma unroll
    for (int r = 0; r < 4; ++r) {
      float s = rsum[r];
      s += __shfl_xor(s, 8, 64);
      s += __shfl_xor(s, 4, 64);
      s += __shfl_xor(s, 2, 64);
      s += __shfl_xor(s, 1, 64);
      l_run[r] += s;
    }
    __syncthreads();
  }
  float inv[4];
#pragma unroll
  for (int r = 0; r < 4; ++r) inv[r] = __builtin_amdgcn_rcpf(l_run[r]);
  float* sOt = (float*)smem;
#pragma unroll
  for (int ct = 0; ct < 4; ++ct)
#pragma unroll
    for (int r = 0; r < 4; ++r)
      sOt[(ct * 16 + l15) * 132 + wave * 16 + quad * 4 + r] = oacc[ct][r] * inv[r];
  __syncthreads();
#pragma unroll
  for (int j = 0; j < 4; ++j) {
    int idx = tid + j * 512;
    int nv = idx & 31, c = idx >> 5;
    float4 o = *(const float4*)&sOt[c * 132 + nv * 4];
    size_t gaddr = (size_t)b * (64 * 4096) + (size_t)c * 4096 + (size_t)(qt * 128 + nv * 4);
    float4 xv = *(const float4*)(x + gaddr);
    float4 res = make_float4(xv.x + o.x, xv.y + o.y, xv.z + o.z, xv.w + o.w);
    *(float4*)(out + gaddr) = res;
  }
}

extern "C" void kernel_launch(void* const* d_in, const int* in_sizes, int n_in,
                              void* d_out, int out_size, void* d_ws, size_t ws_size,
                              hipStream_t stream) {
  const float* xin = (const float*)d_in[0];
  float* out = (float*)d_out;
  if (ws_size >= (size_t)WS_NEED) {
    unsigned short* fbf_t = (unsigned short*)((char*)d_ws + WS_FBF_T);
    unsigned short* fvp = (unsigned short*)((char*)d_ws + WS_FVP);
    float* g = (float*)((char*)d_ws + WS_G);
    float* bmax = (float*)((char*)d_ws + WS_BMAX);
    prep_kernel<<<dim3(512), dim3(512), 0, stream>>>(xin, fbf_t, fvp, g, bmax);
    chanattn_main<<<dim3(256), dim3(512), 0, stream>>>(xin, fbf_t, fvp, g, bmax, out);
  } else {
    chanattn_fallback<<<dim3(256), dim3(512), 0, stream>>>(xin, out);
  }
}